// Round 1
// baseline (1175.999 us; speedup 1.0000x reference)
//
#include <hip/hip_runtime.h>
#include <hip/hip_bf16.h>
#include <cstdint>

#define NTOK   10240      // 5*2048 tokens
#define DIM    1024
#define NEXP   8
#define HDIM   4096
#define NSLOT  20480      // NTOK * top2
#define MAXSLOT 21504     // padded to 128 per expert (168*128)
#define MAXTILES 168

typedef __attribute__((ext_vector_type(8))) __bf16 bf16x8;
typedef __attribute__((ext_vector_type(4))) float  f32x4;

__device__ __forceinline__ unsigned short f2bf(float f){
  uint32_t u = __float_as_uint(f);
  uint32_t r = (u + 0x7fffu + ((u >> 16) & 1u)) >> 16;   // RNE
  return (unsigned short)r;
}

__device__ __forceinline__ void gl_lds16(const void* g, void* l){
  __builtin_amdgcn_global_load_lds(
      (const __attribute__((address_space(1))) void*)g,
      (__attribute__((address_space(3))) void*)l, 16, 0, 0);
}

// ---------------- Threefry2x32 (JAX partitionable path) ----------------
__device__ __forceinline__ uint32_t rotl32(uint32_t x, int n){ return (x << n) | (x >> (32 - n)); }

__device__ __forceinline__ uint32_t threefry_xor(uint32_t k0, uint32_t k1, uint32_t x0, uint32_t x1){
  uint32_t ks2 = k0 ^ k1 ^ 0x1BD11BDAu;
  uint32_t ks[3] = {k0, k1, ks2};
  x0 += ks[0]; x1 += ks[1];
  const int rA[4] = {13,15,26,6};
  const int rB[4] = {17,29,16,24};
  #pragma unroll
  for (int i = 0; i < 5; ++i){
    #pragma unroll
    for (int j = 0; j < 4; ++j){
      int rot = (i & 1) ? rB[j] : rA[j];
      x0 += x1; x1 = rotl32(x1, rot); x1 ^= x0;
    }
    x0 += ks[(i+1)%3];
    x1 += ks[(i+2)%3] + (uint32_t)(i+1);
  }
  return x0 ^ x1;   // partitionable: bits1 ^ bits2 for 32-bit draws
}

// XLA f32 ErfInv (Giles polynomial) — bit-matches jax.lax.erf_inv on f32
__device__ __forceinline__ float erfinv_f32(float x){
  float w = -log1pf(-x*x);
  float p;
  if (w < 5.0f){
    w -= 2.5f;
    p = 2.81022636e-08f;
    p = fmaf(p, w, 3.43273939e-07f);
    p = fmaf(p, w, -3.5233877e-06f);
    p = fmaf(p, w, -4.39150654e-06f);
    p = fmaf(p, w, 0.00021858087f);
    p = fmaf(p, w, -0.00125372503f);
    p = fmaf(p, w, -0.00417768164f);
    p = fmaf(p, w, 0.246640727f);
    p = fmaf(p, w, 1.50140941f);
  } else {
    w = sqrtf(w) - 3.0f;
    p = -0.000200214257f;
    p = fmaf(p, w, 0.000100950558f);
    p = fmaf(p, w, 0.00134934322f);
    p = fmaf(p, w, -0.00367342844f);
    p = fmaf(p, w, 0.00573950773f);
    p = fmaf(p, w, -0.0076224613f);
    p = fmaf(p, w, 0.00943887047f);
    p = fmaf(p, w, 1.00167406f);
    p = fmaf(p, w, 2.83297682f);
  }
  return p * x;
}

// ---------------- elementwise converts ----------------
__global__ void cvt_x_kernel(const float* __restrict__ x, unsigned short* __restrict__ xb){
  size_t i = (size_t)blockIdx.x * 256 + threadIdx.x;   // each handles 4 floats
  float4 v = ((const float4*)x)[i];
  ushort4 o;
  o.x = f2bf(v.x); o.y = f2bf(v.y); o.z = f2bf(v.z); o.w = f2bf(v.w);
  ((ushort4*)xb)[i] = o;
}

// src [z][R_][C_] fp32 -> dst [z][C_][R_] bf16
__global__ void transpose_cvt_kernel(const float* __restrict__ src, unsigned short* __restrict__ dst,
                                     int R_, int C_){
  __shared__ float tile[32][33];
  int z = blockIdx.z;
  const float* s = src + (size_t)z * R_ * C_;
  unsigned short* d = dst + (size_t)z * R_ * C_;
  int c0 = blockIdx.x * 32, r0 = blockIdx.y * 32;
  #pragma unroll
  for (int i = threadIdx.y; i < 32; i += 8)
    tile[i][threadIdx.x] = s[(size_t)(r0 + i) * C_ + c0 + threadIdx.x];
  __syncthreads();
  #pragma unroll
  for (int i = threadIdx.y; i < 32; i += 8)
    d[(size_t)(c0 + i) * R_ + r0 + threadIdx.x] = f2bf(tile[threadIdx.x][i]);
}

// ---------------- routing ----------------
__global__ __launch_bounds__(64) void route_kernel(
    const float* __restrict__ x, const int* __restrict__ moe,
    const float* __restrict__ Wr, const float* __restrict__ br,
    const float* __restrict__ Wn, const float* __restrict__ bn,
    float* __restrict__ topi_out, int* __restrict__ te, float* __restrict__ tgv,
    unsigned* __restrict__ counts)
{
  const int tok = blockIdx.x;
  const int lane = threadIdx.x;
  const int b = tok >> 11;           // /2048
  const int r = moe[b];
  const float* xr  = x  + (size_t)tok * DIM;
  const float* wrp = Wr + (size_t)r * DIM * NEXP;
  const float* wnp = Wn + (size_t)r * DIM * NEXP;

  float lg[NEXP], nl[NEXP];
  #pragma unroll
  for (int e = 0; e < NEXP; ++e){ lg[e] = 0.f; nl[e] = 0.f; }
  for (int it = 0; it < DIM/64; ++it){
    int d = it*64 + lane;
    float xv = xr[d];
    const float* a = wrp + d*NEXP;
    const float* c = wnp + d*NEXP;
    #pragma unroll
    for (int e = 0; e < NEXP; ++e){
      lg[e] = fmaf(xv, a[e], lg[e]);
      nl[e] = fmaf(xv, c[e], nl[e]);
    }
  }
  #pragma unroll
  for (int e = 0; e < NEXP; ++e){
    #pragma unroll
    for (int s = 32; s >= 1; s >>= 1){
      lg[e] += __shfl_xor(lg[e], s, 64);
      nl[e] += __shfl_xor(nl[e], s, 64);
    }
  }
  if (lane == 0){
    float noisy[NEXP];
    #pragma unroll
    for (int e = 0; e < NEXP; ++e){
      float logit = lg[e] + br[r*NEXP + e];
      float nlg   = nl[e] + bn[r*NEXP + e];
      uint32_t idx  = (uint32_t)(tok*NEXP + e);
      uint32_t bits = threefry_xor(0u, 42u, 0u, idx);
      float u01 = __uint_as_float((bits >> 9) | 0x3f800000u) - 1.0f;
      const float lo = -0.99999994f;             // nextafter(-1,0); (hi-lo) folds to 2.0f
      float uu  = fmaxf(lo, u01 * 2.0f + lo);
      float eps = 1.41421356237f * erfinv_f32(uu);
      float ax = fabsf(nlg);
      float sp = fmaxf(nlg, 0.0f) + log1pf(expf(-ax));   // logaddexp(nlg, 0)
      noisy[e] = logit + eps * sp;
    }
    int i0 = 0; float v0 = noisy[0];
    int i1 = -1; float v1 = -3.4e38f;
    #pragma unroll
    for (int e = 1; e < NEXP; ++e){
      float v = noisy[e];
      if (v > v0){ v1 = v0; i1 = i0; v0 = v; i0 = e; }
      else if (v > v1){ v1 = v; i1 = e; }
    }
    float t = expf(v1 - v0);
    float s = 1.0f + t;
    topi_out[tok*2 + 0] = (float)i0;
    topi_out[tok*2 + 1] = (float)i1;
    te[tok*2 + 0] = i0; te[tok*2 + 1] = i1;
    tgv[tok*2 + 0] = 1.0f / s; tgv[tok*2 + 1] = t / s;
    atomicAdd(&counts[i0], 1u);
    atomicAdd(&counts[i1], 1u);
  }
}

// ---------------- tables / scatter ----------------
// hdr layout (unsigned): [0..8) counts, [8..16) cursor, [16] ntiles
__global__ void tables_kernel(unsigned* __restrict__ hdr, int* __restrict__ tile_expert,
                              int* __restrict__ rows, float* __restrict__ gates)
{
  __shared__ unsigned offs_s[NEXP+1];
  __shared__ unsigned cnt_s[NEXP];
  if (threadIdx.x == 0){
    unsigned o = 0, tt = 0;
    for (int e = 0; e < NEXP; ++e){
      unsigned c = hdr[e];
      cnt_s[e] = c;
      offs_s[e] = o;
      hdr[8 + e] = o;                    // cursor init
      unsigned nt = (c + 127u) / 128u;
      for (unsigned k = 0; k < nt; ++k) tile_expert[tt++] = e;
      o += nt * 128u;
    }
    offs_s[NEXP] = o;
    hdr[16] = tt;
  }
  __syncthreads();
  for (int e = 0; e < NEXP; ++e){
    unsigned start = offs_s[e] + cnt_s[e];
    unsigned end   = offs_s[e+1];
    for (unsigned i = start + threadIdx.x; i < end; i += blockDim.x){
      rows[i] = 0; gates[i] = 0.0f;
    }
  }
}

__global__ void scatter_kernel(const int* __restrict__ te, const float* __restrict__ tgv,
                               unsigned* __restrict__ cursor, int* __restrict__ rows,
                               float* __restrict__ gates)
{
  int tok = blockIdx.x * blockDim.x + threadIdx.x;
  if (tok >= NTOK) return;
  #pragma unroll
  for (int k = 0; k < 2; ++k){
    int e = te[tok*2 + k];
    unsigned slot = atomicAdd(&cursor[e], 1u);
    rows[slot]  = tok;
    gates[slot] = tgv[tok*2 + k];
  }
}

// ---------------- grouped GEMMs (m97-style 128x128, BK=64) ----------------
__global__ __launch_bounds__(256) void gemm1_kernel(
    const unsigned short* __restrict__ Xb,   // [NTOK][DIM] bf16
    const unsigned short* __restrict__ W1t,  // [E][HDIM][DIM] bf16 (pre-transposed)
    const float* __restrict__ b1,            // [E][HDIM]
    const int* __restrict__ rows, const int* __restrict__ tile_expert,
    const unsigned* __restrict__ hdr,
    unsigned short* __restrict__ H,          // [chunk_rows][HDIM] bf16
    int tile0)
{
  const int tg = tile0 + (int)blockIdx.x;
  if (tg >= (int)hdr[16]) return;
  const int e  = tile_expert[tg];
  const int n0 = (int)blockIdx.y * 128;
  const int tid = threadIdx.x;
  const int wid = tid >> 6, lane = tid & 63;
  const int wr = wid >> 1, wc = wid & 1;
  const int l8 = lane & 7, ld8 = lane >> 3;

  __shared__ __align__(16) unsigned short As[128][64];
  __shared__ __align__(16) unsigned short Bs[128][64];

  const unsigned short* aSrc[4];
  const unsigned short* bSrc[4];
  #pragma unroll
  for (int i = 0; i < 4; ++i){
    int rrow = (wid*4 + i)*8 + ld8;
    int tokr = rows[tg*128 + rrow];
    aSrc[i] = Xb  + (size_t)tokr * DIM + l8*8;
    bSrc[i] = W1t + ((size_t)e * HDIM + n0 + rrow) * DIM + l8*8;
  }

  f32x4 acc[4][4];
  #pragma unroll
  for (int m = 0; m < 4; ++m)
    #pragma unroll
    for (int n = 0; n < 4; ++n) acc[m][n] = (f32x4)(0.0f);

  for (int kk = 0; kk < DIM; kk += 64){
    #pragma unroll
    for (int i = 0; i < 4; ++i){
      gl_lds16(aSrc[i] + kk, &As[(wid*4 + i)*8][0]);
      gl_lds16(bSrc[i] + kk, &Bs[(wid*4 + i)*8][0]);
    }
    __syncthreads();
    #pragma unroll
    for (int ks = 0; ks < 2; ++ks){
      bf16x8 af[4], bfv[4];
      #pragma unroll
      for (int m = 0; m < 4; ++m)
        af[m] = *reinterpret_cast<const bf16x8*>(&As[wr*64 + m*16 + (lane & 15)][ks*32 + (lane >> 4)*8]);
      #pragma unroll
      for (int n = 0; n < 4; ++n)
        bfv[n] = *reinterpret_cast<const bf16x8*>(&Bs[wc*64 + n*16 + (lane & 15)][ks*32 + (lane >> 4)*8]);
      #pragma unroll
      for (int m = 0; m < 4; ++m)
        #pragma unroll
        for (int n = 0; n < 4; ++n)
          acc[m][n] = __builtin_amdgcn_mfma_f32_16x16x32_bf16(af[m], bfv[n], acc[m][n], 0, 0, 0);
    }
    __syncthreads();
  }

  const int hrow0 = (int)blockIdx.x * 128;  // chunk-local row base
  #pragma unroll
  for (int n = 0; n < 4; ++n){
    int c = n0 + wc*64 + n*16 + (lane & 15);
    float bv = b1[(size_t)e * HDIM + c];
    #pragma unroll
    for (int m = 0; m < 4; ++m){
      #pragma unroll
      for (int j = 0; j < 4; ++j){
        int rloc = wr*64 + m*16 + (lane >> 4)*4 + j;
        float v = fmaxf(acc[m][n][j] + bv, 0.0f);
        H[(size_t)(hrow0 + rloc) * HDIM + c] = f2bf(v);
      }
    }
  }
}

__global__ __launch_bounds__(256) void gemm2_kernel(
    const unsigned short* __restrict__ H,    // [chunk_rows][HDIM] bf16
    const unsigned short* __restrict__ W2t,  // [E][DIM][HDIM] bf16 (pre-transposed)
    const float* __restrict__ b2,            // [E][DIM]
    const int* __restrict__ rows, const float* __restrict__ gates,
    const int* __restrict__ tile_expert, const unsigned* __restrict__ hdr,
    float* __restrict__ out, int tile0)
{
  const int tg = tile0 + (int)blockIdx.x;
  if (tg >= (int)hdr[16]) return;
  const int e  = tile_expert[tg];
  const int n0 = (int)blockIdx.y * 128;
  const int tid = threadIdx.x;
  const int wid = tid >> 6, lane = tid & 63;
  const int wr = wid >> 1, wc = wid & 1;
  const int l8 = lane & 7, ld8 = lane >> 3;

  __shared__ __align__(16) unsigned short As[128][64];
  __shared__ __align__(16) unsigned short Bs[128][64];

  const unsigned short* aSrc[4];
  const unsigned short* bSrc[4];
  #pragma unroll
  for (int i = 0; i < 4; ++i){
    int rrow = (wid*4 + i)*8 + ld8;
    aSrc[i] = H   + (size_t)((int)blockIdx.x*128 + rrow) * HDIM + l8*8;
    bSrc[i] = W2t + ((size_t)e * DIM + n0 + rrow) * HDIM + l8*8;
  }

  f32x4 acc[4][4];
  #pragma unroll
  for (int m = 0; m < 4; ++m)
    #pragma unroll
    for (int n = 0; n < 4; ++n) acc[m][n] = (f32x4)(0.0f);

  for (int kk = 0; kk < HDIM; kk += 64){
    #pragma unroll
    for (int i = 0; i < 4; ++i){
      gl_lds16(aSrc[i] + kk, &As[(wid*4 + i)*8][0]);
      gl_lds16(bSrc[i] + kk, &Bs[(wid*4 + i)*8][0]);
    }
    __syncthreads();
    #pragma unroll
    for (int ks = 0; ks < 2; ++ks){
      bf16x8 af[4], bfv[4];
      #pragma unroll
      for (int m = 0; m < 4; ++m)
        af[m] = *reinterpret_cast<const bf16x8*>(&As[wr*64 + m*16 + (lane & 15)][ks*32 + (lane >> 4)*8]);
      #pragma unroll
      for (int n = 0; n < 4; ++n)
        bfv[n] = *reinterpret_cast<const bf16x8*>(&Bs[wc*64 + n*16 + (lane & 15)][ks*32 + (lane >> 4)*8]);
      #pragma unroll
      for (int m = 0; m < 4; ++m)
        #pragma unroll
        for (int n = 0; n < 4; ++n)
          acc[m][n] = __builtin_amdgcn_mfma_f32_16x16x32_bf16(af[m], bfv[n], acc[m][n], 0, 0, 0);
    }
    __syncthreads();
  }

  #pragma unroll
  for (int m = 0; m < 4; ++m){
    #pragma unroll
    for (int j = 0; j < 4; ++j){
      int r = wr*64 + m*16 + (lane >> 4)*4 + j;
      int slot = tg*128 + r;
      int tokr = rows[slot];
      float gv = gates[slot];
      float* orow = out + (size_t)tokr * DIM;
      #pragma unroll
      for (int n = 0; n < 4; ++n){
        int c = n0 + wc*64 + n*16 + (lane & 15);
        float v = acc[m][n][j] + b2[(size_t)e * DIM + c];
        atomicAdd(&orow[c], gv * v);   // exactly 2 real contributions per element -> deterministic
      }
    }
  }
}

// ---------------- host ----------------
extern "C" void kernel_launch(void* const* d_in, const int* in_sizes, int n_in,
                              void* d_out, int out_size, void* d_ws, size_t ws_size,
                              hipStream_t stream)
{
  const float* x  = (const float*)d_in[0];
  const int*   moe= (const int*)  d_in[1];
  const float* Wr = (const float*)d_in[2];
  const float* br = (const float*)d_in[3];
  const float* Wn = (const float*)d_in[4];
  const float* bn = (const float*)d_in[5];
  const float* W1 = (const float*)d_in[6];
  const float* b1 = (const float*)d_in[7];
  const float* W2 = (const float*)d_in[8];
  const float* b2 = (const float*)d_in[9];
  float* out = (float*)d_out;
  float* topi_out = out + (size_t)NTOK * DIM;

  char* ws = (char*)d_ws;
  size_t off = 0;
  auto take = [&](size_t bytes)->char*{
    char* p = ws + off;
    off = (off + bytes + 255) & ~(size_t)255;
    return p;
  };
  unsigned* hdr        = (unsigned*)take(128);
  int*      tile_exp   = (int*)     take(MAXTILES * 4);
  int*      rows       = (int*)     take(MAXSLOT * 4);
  float*    gates      = (float*)   take(MAXSLOT * 4);
  int*      te         = (int*)     take(NSLOT * 4);
  float*    tgv        = (float*)   take(NSLOT * 4);
  unsigned short* xb   = (unsigned short*)take((size_t)NTOK * DIM * 2);
  unsigned short* W1t  = (unsigned short*)take((size_t)NEXP * HDIM * DIM * 2);
  unsigned short* W2t  = (unsigned short*)take((size_t)NEXP * DIM * HDIM * 2);

  size_t avail = (ws_size > off) ? (ws_size - off) : 0;
  size_t maxrows = avail / ((size_t)HDIM * 2);
  int chunk_rows = (int)((maxrows / 128) * 128);
  if (chunk_rows > MAXSLOT) chunk_rows = MAXSLOT;
  if (chunk_rows < 128)     chunk_rows = 128;   // minimal fallback
  unsigned short* H = (unsigned short*)take((size_t)chunk_rows * HDIM * 2);

  hipMemsetAsync(d_out, 0, (size_t)out_size * 4, stream);
  hipMemsetAsync(hdr, 0, 128, stream);

  cvt_x_kernel<<<NTOK, 256, 0, stream>>>(x, xb);
  dim3 tb(32, 8);
  transpose_cvt_kernel<<<dim3(HDIM/32, DIM/32, NEXP), tb, 0, stream>>>(W1, W1t, DIM, HDIM);
  transpose_cvt_kernel<<<dim3(DIM/32, HDIM/32, NEXP), tb, 0, stream>>>(W2, W2t, HDIM, DIM);
  route_kernel<<<NTOK, 64, 0, stream>>>(x, moe, Wr, br, Wn, bn, topi_out, te, tgv, hdr);
  tables_kernel<<<1, 64, 0, stream>>>(hdr, tile_exp, rows, gates);
  scatter_kernel<<<(NTOK + 255)/256, 256, 0, stream>>>(te, tgv, hdr + 8, rows, gates);

  int tpc = chunk_rows / 128;
  for (int t0 = 0; t0 < MAXTILES; t0 += tpc){
    int nt = (tpc < MAXTILES - t0) ? tpc : (MAXTILES - t0);
    gemm1_kernel<<<dim3(nt, HDIM/128), 256, 0, stream>>>(xb, W1t, b1, rows, tile_exp, hdr, H, t0);
    gemm2_kernel<<<dim3(nt, DIM/128),  256, 0, stream>>>(H, W2t, b2, rows, gates, tile_exp, hdr, out, t0);
  }
}